// Round 9
// baseline (210.189 us; speedup 1.0000x reference)
//
#include <hip/hip_runtime.h>

typedef __attribute__((ext_vector_type(8))) short bf16x8;
typedef __attribute__((ext_vector_type(4))) short bf16x4;
typedef __attribute__((ext_vector_type(4))) float f32x4;

__device__ __forceinline__ float bf2f(unsigned short u) {
    unsigned int x = ((unsigned int)u) << 16;
    float f;
    __builtin_memcpy(&f, &x, 4);
    return f;
}
__device__ __forceinline__ unsigned short f2bf(float f) {
    unsigned int x;
    __builtin_memcpy(&x, &f, 4);
    x += 0x7FFFu + ((x >> 16) & 1u);
    return (unsigned short)(x >> 16);
}

// Async global->LDS: HW writes lds[base + lane*16]; gptr is per-lane.
#define GLOAD_LDS16(gp, lp)                                      \
    __builtin_amdgcn_global_load_lds(                            \
        (const __attribute__((address_space(1))) void*)(gp),     \
        (__attribute__((address_space(3))) void*)(lp), 16, 0, 0)

// -------------------------------------------------------------------------
// Fused preprocessing: one launch instead of three.
// blocks [0,4096):        cast x f32 -> bf16 (4 elems/thread)
// blocks [4096,16384):    fold_lora attn  (3072x1024)
// blocks [16384,20480):   fold_lora proj  (1024x1024)
__global__ __launch_bounds__(256) void prep(
    const float* __restrict__ x, unsigned short* __restrict__ xb,
    const float* __restrict__ w_attn, const float* __restrict__ la_attn,
    const float* __restrict__ lb_attn, unsigned short* __restrict__ Weff_attn,
    const float* __restrict__ w_proj, const float* __restrict__ la_proj,
    const float* __restrict__ lb_proj, unsigned short* __restrict__ Weff_proj) {
    const int bid = blockIdx.x;
    if (bid < 4096) {
        int i = (bid * 256 + threadIdx.x) * 4;
        float4 v = *(const float4*)(x + i);
        xb[i + 0] = f2bf(v.x);
        xb[i + 1] = f2bf(v.y);
        xb[i + 2] = f2bf(v.z);
        xb[i + 3] = f2bf(v.w);
        return;
    }
    const float* W;
    const float* Ain;
    const float* Bin;
    unsigned short* Weff;
    int idx;
    if (bid < 16384) {
        idx = (bid - 4096) * 256 + threadIdx.x;
        W = w_attn; Ain = la_attn; Bin = lb_attn; Weff = Weff_attn;
    } else {
        idx = (bid - 16384) * 256 + threadIdx.x;
        W = w_proj; Ain = la_proj; Bin = lb_proj; Weff = Weff_proj;
    }
    int n = idx >> 10;
    int k = idx & 1023;
    float s = 0.f;
#pragma unroll
    for (int r = 0; r < 16; ++r)
        s += Bin[n * 16 + r] * Ain[r * 1024 + k];
    Weff[idx] = f2bf(W[idx] + 0.0625f * s);
}

// -------------------------------------------------------------------------
// C[M][N] = A[M][K] @ B[N][K]^T + bias[N].  A,B bf16; bias float; fp32 acc.
// m97 structure: global_load_lds width=16 staging, 2 barriers per K-step.
// VSPLIT (qkv GEMM): tiles with n0 >= 2048 are the V third of qkv; written
// transposed directly into Vt (replaces the transpose_v kernel).
template <bool F32OUT, bool VSPLIT>
__global__ __launch_bounds__(256) void gemm_bt_bias(
    const unsigned short* __restrict__ A, const unsigned short* __restrict__ B,
    const float* __restrict__ bias, unsigned short* __restrict__ Cb,
    float* __restrict__ Cf, unsigned short* __restrict__ Vtout,
    int M, int N, int K) {
    __shared__ unsigned short sA[128 * 32];
    __shared__ unsigned short sB[128 * 32];
    const int tid = threadIdx.x;
    const int wave = tid >> 6, lane = tid & 63;
    const int quad = lane >> 4, l16 = lane & 15;
    const int m0 = blockIdx.y * 128, n0 = blockIdx.x * 128;
    const int wm = (wave & 1) * 64, wn = (wave >> 1) * 64;

    const int srow = wave * 32 + (lane >> 2);
    const int scol = (lane & 3) * 8;
    const unsigned short* Ag = A + (size_t)(m0 + srow) * K + scol;
    const unsigned short* Bg = B + (size_t)(n0 + srow) * K + scol;
    unsigned short* sAw = sA + wave * 1024;
    unsigned short* sBw = sB + wave * 1024;
    const size_t kjump = (size_t)16 * K;

    f32x4 acc[4][4];
#pragma unroll
    for (int i = 0; i < 4; ++i)
#pragma unroll
        for (int j = 0; j < 4; ++j) acc[i][j] = (f32x4){0.f, 0.f, 0.f, 0.f};

    for (int k0 = 0; k0 < K; k0 += 32) {
        __syncthreads();  // previous tile's LDS reads done
        GLOAD_LDS16(Ag + k0, sAw);
        GLOAD_LDS16(Ag + k0 + kjump, sAw + 512);
        GLOAD_LDS16(Bg + k0, sBw);
        GLOAD_LDS16(Bg + k0 + kjump, sBw + 512);
        __syncthreads();  // drains vmcnt(0): tile resident
        bf16x8 af[4], bfr[4];
#pragma unroll
        for (int mi = 0; mi < 4; ++mi)
            af[mi] = *(const bf16x8*)&sA[(wm + mi * 16 + l16) * 32 + quad * 8];
#pragma unroll
        for (int ni = 0; ni < 4; ++ni)
            bfr[ni] = *(const bf16x8*)&sB[(wn + ni * 16 + l16) * 32 + quad * 8];
#pragma unroll
        for (int mi = 0; mi < 4; ++mi)
#pragma unroll
            for (int ni = 0; ni < 4; ++ni)
                acc[mi][ni] = __builtin_amdgcn_mfma_f32_16x16x32_bf16(
                    af[mi], bfr[ni], acc[mi][ni], 0, 0, 0);
    }
    float bv[4];
#pragma unroll
    for (int ni = 0; ni < 4; ++ni) bv[ni] = bias[n0 + wn + ni * 16 + l16];

    if (VSPLIT && n0 >= 2048) {
#pragma unroll
        for (int ni = 0; ni < 4; ++ni) {
            const int hcol = n0 + wn + ni * 16 + l16 - 2048;
#pragma unroll
            for (int mi = 0; mi < 4; ++mi) {
                const int rowtop = m0 + wm + mi * 16 + quad * 4;
                const int bb = rowtop >> 11;
                const int t = rowtop & 2047;
                bf16x4 pk;
#pragma unroll
                for (int r = 0; r < 4; ++r)
                    pk[r] = (short)f2bf(acc[mi][ni][r] + bv[ni]);
                *(bf16x4*)(Vtout +
                           ((size_t)((bb * 16 + (hcol >> 6)) * 64 + (hcol & 63))) *
                               2048 +
                           t) = pk;
            }
        }
        return;
    }

#pragma unroll
    for (int mi = 0; mi < 4; ++mi)
#pragma unroll
        for (int ni = 0; ni < 4; ++ni)
#pragma unroll
            for (int r = 0; r < 4; ++r) {
                int row = m0 + wm + mi * 16 + quad * 4 + r;
                int col = n0 + wn + ni * 16 + l16;
                float val = acc[mi][ni][r] + bv[ni];
                if (F32OUT)
                    Cf[(size_t)row * N + col] = val;
                else
                    Cb[(size_t)row * N + col] = f2bf(val);
            }
}

// -------------------------------------------------------------------------
// BM=64 variant for the proj GEMM: 64x128 tile, 4 waves of 64x32, acc 4x2.
// Grid (N/128, M/64) = (8,64) = 512 blocks = 2 blocks/CU (was 1 with 128^2).
__global__ __launch_bounds__(256) void gemm_bt_bias64(
    const unsigned short* __restrict__ A, const unsigned short* __restrict__ B,
    const float* __restrict__ bias, float* __restrict__ Cf,
    int M, int N, int K) {
    __shared__ unsigned short sA[64 * 32];
    __shared__ unsigned short sB[128 * 32];
    const int tid = threadIdx.x;
    const int wave = tid >> 6, lane = tid & 63;
    const int quad = lane >> 4, l16 = lane & 15;
    const int m0 = blockIdx.y * 64, n0 = blockIdx.x * 128;
    const int wn = wave * 32;

    const int srowA = wave * 16 + (lane >> 2);
    const int srowB = wave * 32 + (lane >> 2);
    const int scol = (lane & 3) * 8;
    const unsigned short* Ag = A + (size_t)(m0 + srowA) * K + scol;
    const unsigned short* Bg = B + (size_t)(n0 + srowB) * K + scol;
    unsigned short* sAw = sA + wave * 512;
    unsigned short* sBw = sB + wave * 1024;
    const size_t kjump = (size_t)16 * K;

    f32x4 acc[4][2];
#pragma unroll
    for (int i = 0; i < 4; ++i)
#pragma unroll
        for (int j = 0; j < 2; ++j) acc[i][j] = (f32x4){0.f, 0.f, 0.f, 0.f};

    for (int k0 = 0; k0 < K; k0 += 32) {
        __syncthreads();
        GLOAD_LDS16(Ag + k0, sAw);
        GLOAD_LDS16(Bg + k0, sBw);
        GLOAD_LDS16(Bg + k0 + kjump, sBw + 512);
        __syncthreads();
        bf16x8 af[4], bfr[2];
#pragma unroll
        for (int mi = 0; mi < 4; ++mi)
            af[mi] = *(const bf16x8*)&sA[(mi * 16 + l16) * 32 + quad * 8];
#pragma unroll
        for (int ni = 0; ni < 2; ++ni)
            bfr[ni] = *(const bf16x8*)&sB[(wn + ni * 16 + l16) * 32 + quad * 8];
#pragma unroll
        for (int mi = 0; mi < 4; ++mi)
#pragma unroll
            for (int ni = 0; ni < 2; ++ni)
                acc[mi][ni] = __builtin_amdgcn_mfma_f32_16x16x32_bf16(
                    af[mi], bfr[ni], acc[mi][ni], 0, 0, 0);
    }
    float bv[2];
#pragma unroll
    for (int ni = 0; ni < 2; ++ni) bv[ni] = bias[n0 + wn + ni * 16 + l16];
#pragma unroll
    for (int mi = 0; mi < 4; ++mi)
#pragma unroll
        for (int ni = 0; ni < 2; ++ni)
#pragma unroll
            for (int r = 0; r < 4; ++r) {
                int row = m0 + mi * 16 + quad * 4 + r;
                int col = n0 + wn + ni * 16 + l16;
                Cf[(size_t)row * N + col] = acc[mi][ni][r] + bv[ni];
            }
}

// -------------------------------------------------------------------------
// Flash attention v10: 2 q-fragments per wave, shared K/V fragments.
// v9 was LDS-throughput-bound: 26 DS ops/wave-tile x 66 tile-units/CU x 4
// waves ~= 36 us of LDS-pipe time (all 4 waves read the ENTIRE K,V tile;
// reads don't amortize across q). Now each wave computes 32 q-rows as two
// 16-row fragments sharing one set of K-frags (MFMA A-operand) and V-frags:
// 32 DS ops for 2x the q-work, and blocks cover 128 q-rows -> tile-units
// per CU drop 66 -> 34. Total LDS instr: 0.63x. K/V HBM refetch halves.
// Grid (16,16,2) = 512 blocks = 2/CU; balance: qblk = x ^ (z?15:0) gives
// each CU pair {2x+2, 32-2x} = 34 tile-units (uniform; LDS-bound regime
// follows total units). Softmax: swapped-QK^T in-register (v7).
__global__ __launch_bounds__(256) void attn_kernel(
    const unsigned short* __restrict__ qkv,  // [4096][3072] bf16
    const unsigned short* __restrict__ Vt,   // [32][64][2048] bf16
    unsigned short* __restrict__ y) {        // [4096][1024] bf16
    const int b = blockIdx.z, h = blockIdx.y;
    const int bh = b * 16 + h;
    const int qblk = (int)blockIdx.x ^ (b ? 15 : 0);  // co-resident balance
    const int w = threadIdx.x >> 6, lane = threadIdx.x & 63;
    const int quad = lane >> 4, l16 = lane & 15;
    const int qA = qblk * 128 + w * 32;  // frag A: rows qA..qA+15
    const int qB = qA + 16;              // frag B: rows qB..qB+15
    const int ntiles = 2 * qblk + 2;

    __shared__ unsigned short sK[64 * 72];     // [kv][d]
    __shared__ unsigned short sV[64 * 72];     // [d][kv]
    __shared__ unsigned short sP[4][32 * 72];  // per-wave P [32 q][kv]

    const unsigned short* Qb = qkv + (size_t)(b * 2048) * 3072 + h * 64;
    const unsigned short* Kg = Qb + 1024;
    const unsigned short* Vg = Vt + (size_t)(bh * 64) * 2048;

    const int rlo = threadIdx.x >> 3;       // 0..31
    const int c8 = (threadIdx.x & 7) * 8;   // 0..56

    bf16x8 qa0 = *(const bf16x8*)(Qb + (size_t)(qA + l16) * 3072 + quad * 8);
    bf16x8 qa1 = *(const bf16x8*)(Qb + (size_t)(qA + l16) * 3072 + 32 + quad * 8);
    bf16x8 qb0 = *(const bf16x8*)(Qb + (size_t)(qB + l16) * 3072 + quad * 8);
    bf16x8 qb1 = *(const bf16x8*)(Qb + (size_t)(qB + l16) * 3072 + 32 + quad * 8);

    f32x4 oA[4], oB[4];
    float laccA = 0.f, laccB = 0.f;
#pragma unroll
    for (int nt = 0; nt < 4; ++nt) {
        oA[nt] = (f32x4){0.f, 0.f, 0.f, 0.f};
        oB[nt] = (f32x4){0.f, 0.f, 0.f, 0.f};
    }

    const float csc = 0.125f * 1.44269504088896340736f;  // (1/sqrt 64)*log2(e)

    bf16x8 kr0 = *(const bf16x8*)(Kg + (size_t)rlo * 3072 + c8);
    bf16x8 kr1 = *(const bf16x8*)(Kg + (size_t)(rlo + 32) * 3072 + c8);
    bf16x8 vr0 = *(const bf16x8*)(Vg + (size_t)rlo * 2048 + c8);
    bf16x8 vr1 = *(const bf16x8*)(Vg + (size_t)(rlo + 32) * 2048 + c8);

    for (int it = 0; it < ntiles; ++it) {
        const int kv0 = it * 64;
        __syncthreads();  // buffer free; drains last iter's prefetch
        *(bf16x8*)&sK[rlo * 72 + c8] = kr0;
        *(bf16x8*)&sK[(rlo + 32) * 72 + c8] = kr1;
        *(bf16x8*)&sV[rlo * 72 + c8] = vr0;
        *(bf16x8*)&sV[(rlo + 32) * 72 + c8] = vr1;
        __syncthreads();  // buffer ready
        if (it + 1 < ntiles) {  // prefetch next tile: flies during compute
            const int nx = kv0 + 64;
            kr0 = *(const bf16x8*)(Kg + (size_t)(nx + rlo) * 3072 + c8);
            kr1 = *(const bf16x8*)(Kg + (size_t)(nx + rlo + 32) * 3072 + c8);
            vr0 = *(const bf16x8*)(Vg + (size_t)rlo * 2048 + nx + c8);
            vr1 = *(const bf16x8*)(Vg + (size_t)(rlo + 32) * 2048 + nx + c8);
        }

        // S^T: q = qX+l16, kv = kv0 + f*16 + quad*4 + r. K-frags SHARED.
        f32x4 SA[4], SB[4];
#pragma unroll
        for (int f = 0; f < 4; ++f) {
            bf16x8 klo = *(const bf16x8*)&sK[(f * 16 + l16) * 72 + quad * 8];
            bf16x8 khi = *(const bf16x8*)&sK[(f * 16 + l16) * 72 + 32 + quad * 8];
            SA[f] = (f32x4){0.f, 0.f, 0.f, 0.f};
            SA[f] = __builtin_amdgcn_mfma_f32_16x16x32_bf16(klo, qa0, SA[f], 0, 0, 0);
            SA[f] = __builtin_amdgcn_mfma_f32_16x16x32_bf16(khi, qa1, SA[f], 0, 0, 0);
            SB[f] = (f32x4){0.f, 0.f, 0.f, 0.f};
            SB[f] = __builtin_amdgcn_mfma_f32_16x16x32_bf16(klo, qb0, SB[f], 0, 0, 0);
            SB[f] = __builtin_amdgcn_mfma_f32_16x16x32_bf16(khi, qb1, SB[f], 0, 0, 0);
        }
        const bool diag = (it >= 2 * qblk);  // only last two tiles need mask
#pragma unroll
        for (int X = 0; X < 2; ++X) {
            const int qr = (X ? qB : qA) + l16;
            const int rowbase = X ? 16 : 0;
            float* lp = X ? &laccB : &laccA;
#pragma unroll
            for (int f = 0; f < 4; ++f) {
                f32x4 Sf = X ? SB[f] : SA[f];
                float p0, p1, p2, p3;
                {
                    float sv = Sf[0] * csc;
                    asm("v_exp_f32 %0, %1" : "=v"(p0) : "v"(sv));
                    sv = Sf[1] * csc;
                    asm("v_exp_f32 %0, %1" : "=v"(p1) : "v"(sv));
                    sv = Sf[2] * csc;
                    asm("v_exp_f32 %0, %1" : "=v"(p2) : "v"(sv));
                    sv = Sf[3] * csc;
                    asm("v_exp_f32 %0, %1" : "=v"(p3) : "v"(sv));
                }
                if (diag) {  // mask: kv <= q (absolute indices)
                    int c = kv0 + f * 16 + quad * 4;
                    p0 = (c + 0 <= qr) ? p0 : 0.f;
                    p1 = (c + 1 <= qr) ? p1 : 0.f;
                    p2 = (c + 2 <= qr) ? p2 : 0.f;
                    p3 = (c + 3 <= qr) ? p3 : 0.f;
                }
                *lp += (p0 + p1) + (p2 + p3);
                unsigned int d0, d1;
                asm("v_cvt_pk_bf16_f32 %0, %1, %2" : "=v"(d0) : "v"(p0), "v"(p1));
                asm("v_cvt_pk_bf16_f32 %0, %1, %2" : "=v"(d1) : "v"(p2), "v"(p3));
                *(uint2*)&sP[w][(rowbase + l16) * 72 + f * 16 + quad * 4] =
                    (uint2){d0, d1};
            }
        }
        asm volatile("" ::: "memory");  // order P stores before reload
        bf16x8 pfA0 = *(const bf16x8*)&sP[w][l16 * 72 + quad * 8];
        bf16x8 pfA1 = *(const bf16x8*)&sP[w][l16 * 72 + 32 + quad * 8];
        bf16x8 pfB0 = *(const bf16x8*)&sP[w][(16 + l16) * 72 + quad * 8];
        bf16x8 pfB1 = *(const bf16x8*)&sP[w][(16 + l16) * 72 + 32 + quad * 8];
#pragma unroll
        for (int nt = 0; nt < 4; ++nt) {
            bf16x8 v0 = *(const bf16x8*)&sV[(nt * 16 + l16) * 72 + quad * 8];
            bf16x8 v1 = *(const bf16x8*)&sV[(nt * 16 + l16) * 72 + 32 + quad * 8];
            oA[nt] = __builtin_amdgcn_mfma_f32_16x16x32_bf16(pfA0, v0, oA[nt], 0, 0, 0);
            oA[nt] = __builtin_amdgcn_mfma_f32_16x16x32_bf16(pfA1, v1, oA[nt], 0, 0, 0);
            oB[nt] = __builtin_amdgcn_mfma_f32_16x16x32_bf16(pfB0, v0, oB[nt], 0, 0, 0);
            oB[nt] = __builtin_amdgcn_mfma_f32_16x16x32_bf16(pfB1, v1, oB[nt], 0, 0, 0);
        }
    }

    // Denominators: laccX is partial for q = qX+l16; reduce over quads, then
    // redistribute to output rows (qX + quad*4 + r lives in lane l16=quad*4+r).
    laccA += __shfl_xor(laccA, 16);
    laccA += __shfl_xor(laccA, 32);
    laccB += __shfl_xor(laccB, 16);
    laccB += __shfl_xor(laccB, 32);
    float ltA[4], ltB[4];
#pragma unroll
    for (int r = 0; r < 4; ++r) {
        ltA[r] = __shfl(laccA, quad * 4 + r);
        ltB[r] = __shfl(laccB, quad * 4 + r);
    }

    unsigned short* yb = y + (size_t)(b * 2048) * 1024 + h * 64;
#pragma unroll
    for (int nt = 0; nt < 4; ++nt)
#pragma unroll
        for (int r = 0; r < 4; ++r) {
            yb[(size_t)(qA + quad * 4 + r) * 1024 + nt * 16 + l16] =
                f2bf(oA[nt][r] / ltA[r]);
            yb[(size_t)(qB + quad * 4 + r) * 1024 + nt * 16 + l16] =
                f2bf(oB[nt][r] / ltB[r]);
        }
}

// -------------------------------------------------------------------------
extern "C" void kernel_launch(void* const* d_in, const int* in_sizes, int n_in,
                              void* d_out, int out_size, void* d_ws, size_t ws_size,
                              hipStream_t stream) {
    const float* x       = (const float*)d_in[0];
    const float* w_attn  = (const float*)d_in[1];
    const float* b_attn  = (const float*)d_in[2];
    const float* la_attn = (const float*)d_in[3];
    const float* lb_attn = (const float*)d_in[4];
    const float* w_proj  = (const float*)d_in[5];
    const float* b_proj  = (const float*)d_in[6];
    const float* la_proj = (const float*)d_in[7];
    const float* lb_proj = (const float*)d_in[8];
    float* out = (float*)d_out;

    char* w = (char*)d_ws;
    unsigned short* xb        = (unsigned short*)w; w += (size_t)4096 * 1024 * 2;
    unsigned short* Weff_attn = (unsigned short*)w; w += (size_t)3072 * 1024 * 2;
    unsigned short* Weff_proj = (unsigned short*)w; w += (size_t)1024 * 1024 * 2;
    unsigned short* qkv       = (unsigned short*)w; w += (size_t)4096 * 3072 * 2;
    unsigned short* Vt        = (unsigned short*)w; w += (size_t)32 * 64 * 2048 * 2;
    unsigned short* y         = (unsigned short*)w; w += (size_t)4096 * 1024 * 2;

    prep<<<20480, 256, 0, stream>>>(x, xb, w_attn, la_attn, lb_attn, Weff_attn,
                                    w_proj, la_proj, lb_proj, Weff_proj);
    gemm_bt_bias<false, true><<<dim3(24, 32), 256, 0, stream>>>(
        xb, Weff_attn, b_attn, qkv, (float*)nullptr, Vt, 4096, 3072, 1024);
    attn_kernel<<<dim3(16, 16, 2), 256, 0, stream>>>(qkv, Vt, y);
    gemm_bt_bias64<<<dim3(8, 64), 256, 0, stream>>>(
        y, Weff_proj, b_proj, out, 4096, 1024, 1024);
}

// Round 10
// 199.095 us; speedup vs baseline: 1.0557x; 1.0557x over previous
//
#include <hip/hip_runtime.h>

typedef __attribute__((ext_vector_type(8))) short bf16x8;
typedef __attribute__((ext_vector_type(4))) short bf16x4;
typedef __attribute__((ext_vector_type(4))) float f32x4;

__device__ __forceinline__ float bf2f(unsigned short u) {
    unsigned int x = ((unsigned int)u) << 16;
    float f;
    __builtin_memcpy(&f, &x, 4);
    return f;
}
__device__ __forceinline__ unsigned short f2bf(float f) {
    unsigned int x;
    __builtin_memcpy(&x, &f, 4);
    x += 0x7FFFu + ((x >> 16) & 1u);
    return (unsigned short)(x >> 16);
}

// Async global->LDS: HW writes lds[base + lane*16]; gptr is per-lane.
#define GLOAD_LDS16(gp, lp)                                      \
    __builtin_amdgcn_global_load_lds(                            \
        (const __attribute__((address_space(1))) void*)(gp),     \
        (__attribute__((address_space(3))) void*)(lp), 16, 0, 0)

// -------------------------------------------------------------------------
// Fused preprocessing, G13-vectorized: 8 elems/thread, float4 x2 loads,
// one 16B bf16x8 store.
// blocks [0,2048):       cast x f32 -> bf16      (4096x1024)
// blocks [2048,3584):    fold_lora attn          (3072x1024)
// blocks [3584,4096):    fold_lora proj          (1024x1024)
__global__ __launch_bounds__(256) void prep(
    const float* __restrict__ x, unsigned short* __restrict__ xb,
    const float* __restrict__ w_attn, const float* __restrict__ la_attn,
    const float* __restrict__ lb_attn, unsigned short* __restrict__ Weff_attn,
    const float* __restrict__ w_proj, const float* __restrict__ la_proj,
    const float* __restrict__ lb_proj, unsigned short* __restrict__ Weff_proj) {
    const int bid = blockIdx.x;
    if (bid < 2048) {
        int i = (bid * 256 + threadIdx.x) * 8;
        float4 v0 = *(const float4*)(x + i);
        float4 v1 = *(const float4*)(x + i + 4);
        bf16x8 o;
        o[0] = (short)f2bf(v0.x); o[1] = (short)f2bf(v0.y);
        o[2] = (short)f2bf(v0.z); o[3] = (short)f2bf(v0.w);
        o[4] = (short)f2bf(v1.x); o[5] = (short)f2bf(v1.y);
        o[6] = (short)f2bf(v1.z); o[7] = (short)f2bf(v1.w);
        *(bf16x8*)(xb + i) = o;
        return;
    }
    const float* W;
    const float* Ain;
    const float* Bin;
    unsigned short* Weff;
    int idx;
    if (bid < 3584) {
        idx = ((bid - 2048) * 256 + threadIdx.x) * 8;
        W = w_attn; Ain = la_attn; Bin = lb_attn; Weff = Weff_attn;
    } else {
        idx = ((bid - 3584) * 256 + threadIdx.x) * 8;
        W = w_proj; Ain = la_proj; Bin = lb_proj; Weff = Weff_proj;
    }
    const int n = idx >> 10;
    const int k = idx & 1023;
    float s[8];
#pragma unroll
    for (int j = 0; j < 8; ++j) s[j] = 0.f;
#pragma unroll
    for (int r = 0; r < 16; ++r) {
        const float bcoef = Bin[n * 16 + r];
        float4 a0 = *(const float4*)(Ain + r * 1024 + k);
        float4 a1 = *(const float4*)(Ain + r * 1024 + k + 4);
        s[0] += bcoef * a0.x; s[1] += bcoef * a0.y;
        s[2] += bcoef * a0.z; s[3] += bcoef * a0.w;
        s[4] += bcoef * a1.x; s[5] += bcoef * a1.y;
        s[6] += bcoef * a1.z; s[7] += bcoef * a1.w;
    }
    float4 w0 = *(const float4*)(W + idx);
    float4 w1 = *(const float4*)(W + idx + 4);
    bf16x8 o;
    o[0] = (short)f2bf(w0.x + 0.0625f * s[0]);
    o[1] = (short)f2bf(w0.y + 0.0625f * s[1]);
    o[2] = (short)f2bf(w0.z + 0.0625f * s[2]);
    o[3] = (short)f2bf(w0.w + 0.0625f * s[3]);
    o[4] = (short)f2bf(w1.x + 0.0625f * s[4]);
    o[5] = (short)f2bf(w1.y + 0.0625f * s[5]);
    o[6] = (short)f2bf(w1.z + 0.0625f * s[6]);
    o[7] = (short)f2bf(w1.w + 0.0625f * s[7]);
    *(bf16x8*)(Weff + idx) = o;
}

// -------------------------------------------------------------------------
// C[M][N] = A[M][K] @ B[N][K]^T + bias[N].  A,B bf16; bias float; fp32 acc.
// m97 structure: global_load_lds width=16 staging, 2 barriers per K-step.
// VSPLIT (qkv GEMM): tiles with n0 >= 2048 are the V third of qkv; written
// transposed directly into Vt (replaces the transpose_v kernel).
template <bool F32OUT, bool VSPLIT>
__global__ __launch_bounds__(256) void gemm_bt_bias(
    const unsigned short* __restrict__ A, const unsigned short* __restrict__ B,
    const float* __restrict__ bias, unsigned short* __restrict__ Cb,
    float* __restrict__ Cf, unsigned short* __restrict__ Vtout,
    int M, int N, int K) {
    __shared__ unsigned short sA[128 * 32];
    __shared__ unsigned short sB[128 * 32];
    const int tid = threadIdx.x;
    const int wave = tid >> 6, lane = tid & 63;
    const int quad = lane >> 4, l16 = lane & 15;
    const int m0 = blockIdx.y * 128, n0 = blockIdx.x * 128;
    const int wm = (wave & 1) * 64, wn = (wave >> 1) * 64;

    const int srow = wave * 32 + (lane >> 2);
    const int scol = (lane & 3) * 8;
    const unsigned short* Ag = A + (size_t)(m0 + srow) * K + scol;
    const unsigned short* Bg = B + (size_t)(n0 + srow) * K + scol;
    unsigned short* sAw = sA + wave * 1024;
    unsigned short* sBw = sB + wave * 1024;
    const size_t kjump = (size_t)16 * K;

    f32x4 acc[4][4];
#pragma unroll
    for (int i = 0; i < 4; ++i)
#pragma unroll
        for (int j = 0; j < 4; ++j) acc[i][j] = (f32x4){0.f, 0.f, 0.f, 0.f};

    for (int k0 = 0; k0 < K; k0 += 32) {
        __syncthreads();  // previous tile's LDS reads done
        GLOAD_LDS16(Ag + k0, sAw);
        GLOAD_LDS16(Ag + k0 + kjump, sAw + 512);
        GLOAD_LDS16(Bg + k0, sBw);
        GLOAD_LDS16(Bg + k0 + kjump, sBw + 512);
        __syncthreads();  // drains vmcnt(0): tile resident
        bf16x8 af[4], bfr[4];
#pragma unroll
        for (int mi = 0; mi < 4; ++mi)
            af[mi] = *(const bf16x8*)&sA[(wm + mi * 16 + l16) * 32 + quad * 8];
#pragma unroll
        for (int ni = 0; ni < 4; ++ni)
            bfr[ni] = *(const bf16x8*)&sB[(wn + ni * 16 + l16) * 32 + quad * 8];
#pragma unroll
        for (int mi = 0; mi < 4; ++mi)
#pragma unroll
            for (int ni = 0; ni < 4; ++ni)
                acc[mi][ni] = __builtin_amdgcn_mfma_f32_16x16x32_bf16(
                    af[mi], bfr[ni], acc[mi][ni], 0, 0, 0);
    }
    float bv[4];
#pragma unroll
    for (int ni = 0; ni < 4; ++ni) bv[ni] = bias[n0 + wn + ni * 16 + l16];

    if (VSPLIT && n0 >= 2048) {
#pragma unroll
        for (int ni = 0; ni < 4; ++ni) {
            const int hcol = n0 + wn + ni * 16 + l16 - 2048;
#pragma unroll
            for (int mi = 0; mi < 4; ++mi) {
                const int rowtop = m0 + wm + mi * 16 + quad * 4;
                const int bb = rowtop >> 11;
                const int t = rowtop & 2047;
                bf16x4 pk;
#pragma unroll
                for (int r = 0; r < 4; ++r)
                    pk[r] = (short)f2bf(acc[mi][ni][r] + bv[ni]);
                *(bf16x4*)(Vtout +
                           ((size_t)((bb * 16 + (hcol >> 6)) * 64 + (hcol & 63))) *
                               2048 +
                           t) = pk;
            }
        }
        return;
    }

#pragma unroll
    for (int mi = 0; mi < 4; ++mi)
#pragma unroll
        for (int ni = 0; ni < 4; ++ni)
#pragma unroll
            for (int r = 0; r < 4; ++r) {
                int row = m0 + wm + mi * 16 + quad * 4 + r;
                int col = n0 + wn + ni * 16 + l16;
                float val = acc[mi][ni][r] + bv[ni];
                if (F32OUT)
                    Cf[(size_t)row * N + col] = val;
                else
                    Cb[(size_t)row * N + col] = f2bf(val);
            }
}

// -------------------------------------------------------------------------
// BM=64 variant for the proj GEMM: 64x128 tile, 4 waves of 64x32, acc 4x2.
// Grid (N/128, M/64) = (8,64) = 512 blocks = 2 blocks/CU (was 1 with 128^2).
__global__ __launch_bounds__(256) void gemm_bt_bias64(
    const unsigned short* __restrict__ A, const unsigned short* __restrict__ B,
    const float* __restrict__ bias, float* __restrict__ Cf,
    int M, int N, int K) {
    __shared__ unsigned short sA[64 * 32];
    __shared__ unsigned short sB[128 * 32];
    const int tid = threadIdx.x;
    const int wave = tid >> 6, lane = tid & 63;
    const int quad = lane >> 4, l16 = lane & 15;
    const int m0 = blockIdx.y * 64, n0 = blockIdx.x * 128;
    const int wn = wave * 32;

    const int srowA = wave * 16 + (lane >> 2);
    const int srowB = wave * 32 + (lane >> 2);
    const int scol = (lane & 3) * 8;
    const unsigned short* Ag = A + (size_t)(m0 + srowA) * K + scol;
    const unsigned short* Bg = B + (size_t)(n0 + srowB) * K + scol;
    unsigned short* sAw = sA + wave * 512;
    unsigned short* sBw = sB + wave * 1024;
    const size_t kjump = (size_t)16 * K;

    f32x4 acc[4][2];
#pragma unroll
    for (int i = 0; i < 4; ++i)
#pragma unroll
        for (int j = 0; j < 2; ++j) acc[i][j] = (f32x4){0.f, 0.f, 0.f, 0.f};

    for (int k0 = 0; k0 < K; k0 += 32) {
        __syncthreads();
        GLOAD_LDS16(Ag + k0, sAw);
        GLOAD_LDS16(Bg + k0, sBw);
        GLOAD_LDS16(Bg + k0 + kjump, sBw + 512);
        __syncthreads();
        bf16x8 af[4], bfr[2];
#pragma unroll
        for (int mi = 0; mi < 4; ++mi)
            af[mi] = *(const bf16x8*)&sA[(mi * 16 + l16) * 32 + quad * 8];
#pragma unroll
        for (int ni = 0; ni < 2; ++ni)
            bfr[ni] = *(const bf16x8*)&sB[(wn + ni * 16 + l16) * 32 + quad * 8];
#pragma unroll
        for (int mi = 0; mi < 4; ++mi)
#pragma unroll
            for (int ni = 0; ni < 2; ++ni)
                acc[mi][ni] = __builtin_amdgcn_mfma_f32_16x16x32_bf16(
                    af[mi], bfr[ni], acc[mi][ni], 0, 0, 0);
    }
    float bv[2];
#pragma unroll
    for (int ni = 0; ni < 2; ++ni) bv[ni] = bias[n0 + wn + ni * 16 + l16];
#pragma unroll
    for (int mi = 0; mi < 4; ++mi)
#pragma unroll
        for (int ni = 0; ni < 2; ++ni)
#pragma unroll
            for (int r = 0; r < 4; ++r) {
                int row = m0 + mi * 16 + quad * 4 + r;
                int col = n0 + wn + ni * 16 + l16;
                Cf[(size_t)row * N + col] = acc[mi][ni][r] + bv[ni];
            }
}

// -------------------------------------------------------------------------
// Flash attention v9 (reverted from v10): r3 scheduling (grid 32, balanced
// qblk permutation, 4 blocks/CU) + swapped-QK^T in-register softmax +
// prefetch issued after the second barrier. v10 (2 q-frags/wave) regressed:
// it kept the 32-tile critical path while doubling per-tile latency and
// halving residency (occupancy 24% -> 12.6%).
__global__ __launch_bounds__(256) void attn_kernel(
    const unsigned short* __restrict__ qkv,  // [4096][3072] bf16
    const unsigned short* __restrict__ Vt,   // [32][64][2048] bf16
    unsigned short* __restrict__ y) {        // [4096][1024] bf16
    const int b = blockIdx.z, h = blockIdx.y;
    const int bh = b * 16 + h;
    const int qblk = (int)blockIdx.x ^ (((bh >> 3) & 1) ? 31 : 0);
    const int w = threadIdx.x >> 6, lane = threadIdx.x & 63;
    const int quad = lane >> 4, l16 = lane & 15;
    const int q0 = qblk * 64 + w * 16;
    const int ntiles = qblk + 1;

    __shared__ unsigned short sK[64 * 72];     // [kv][d]
    __shared__ unsigned short sV[64 * 72];     // [d][kv]
    __shared__ unsigned short sP[4][16 * 72];  // per-wave P [q][kv]

    const unsigned short* Qb = qkv + (size_t)(b * 2048) * 3072 + h * 64;
    const unsigned short* Kg = Qb + 1024;
    const unsigned short* Vg = Vt + (size_t)(bh * 64) * 2048;

    const int rlo = threadIdx.x >> 3;       // 0..31
    const int c8 = (threadIdx.x & 7) * 8;   // 0..56

    bf16x8 qf0 = *(const bf16x8*)(Qb + (size_t)(q0 + l16) * 3072 + quad * 8);
    bf16x8 qf1 = *(const bf16x8*)(Qb + (size_t)(q0 + l16) * 3072 + 32 + quad * 8);

    f32x4 o[4];
    float lacc = 0.f;  // scalar: all this thread's P values belong to q=q0+l16
#pragma unroll
    for (int nt = 0; nt < 4; ++nt) o[nt] = (f32x4){0.f, 0.f, 0.f, 0.f};

    const float csc = 0.125f * 1.44269504088896340736f;  // (1/sqrt 64)*log2(e)

    bf16x8 kr0 = *(const bf16x8*)(Kg + (size_t)rlo * 3072 + c8);
    bf16x8 kr1 = *(const bf16x8*)(Kg + (size_t)(rlo + 32) * 3072 + c8);
    bf16x8 vr0 = *(const bf16x8*)(Vg + (size_t)rlo * 2048 + c8);
    bf16x8 vr1 = *(const bf16x8*)(Vg + (size_t)(rlo + 32) * 2048 + c8);

    for (int it = 0; it < ntiles; ++it) {
        const int kv0 = it * 64;
        __syncthreads();  // buffer free; drains last iter's prefetch (cheap)
        *(bf16x8*)&sK[rlo * 72 + c8] = kr0;
        *(bf16x8*)&sK[(rlo + 32) * 72 + c8] = kr1;
        *(bf16x8*)&sV[rlo * 72 + c8] = vr0;
        *(bf16x8*)&sV[(rlo + 32) * 72 + c8] = vr1;
        __syncthreads();  // buffer ready (no vmem outstanding here)
        if (it + 1 < ntiles) {  // prefetch next tile: in flight during compute
            const int nx = kv0 + 64;
            kr0 = *(const bf16x8*)(Kg + (size_t)(nx + rlo) * 3072 + c8);
            kr1 = *(const bf16x8*)(Kg + (size_t)(nx + rlo + 32) * 3072 + c8);
            vr0 = *(const bf16x8*)(Vg + (size_t)rlo * 2048 + nx + c8);
            vr1 = *(const bf16x8*)(Vg + (size_t)(rlo + 32) * 2048 + nx + c8);
        }

        // S^T[f][r]: q = q0+l16, kv = kv0 + f*16 + quad*4 + r
        f32x4 S[4];
#pragma unroll
        for (int f = 0; f < 4; ++f) {
            bf16x8 klo = *(const bf16x8*)&sK[(f * 16 + l16) * 72 + quad * 8];
            bf16x8 khi = *(const bf16x8*)&sK[(f * 16 + l16) * 72 + 32 + quad * 8];
            S[f] = (f32x4){0.f, 0.f, 0.f, 0.f};
            S[f] = __builtin_amdgcn_mfma_f32_16x16x32_bf16(klo, qf0, S[f], 0, 0, 0);
            S[f] = __builtin_amdgcn_mfma_f32_16x16x32_bf16(khi, qf1, S[f], 0, 0, 0);
        }
        const bool diag = (it == qblk);
        const int qr16 = w * 16 + l16;  // q position within the 64-row block
#pragma unroll
        for (int f = 0; f < 4; ++f) {
            float p0, p1, p2, p3;
            {
                float sv = S[f][0] * csc;
                asm("v_exp_f32 %0, %1" : "=v"(p0) : "v"(sv));
                sv = S[f][1] * csc;
                asm("v_exp_f32 %0, %1" : "=v"(p1) : "v"(sv));
                sv = S[f][2] * csc;
                asm("v_exp_f32 %0, %1" : "=v"(p2) : "v"(sv));
                sv = S[f][3] * csc;
                asm("v_exp_f32 %0, %1" : "=v"(p3) : "v"(sv));
            }
            if (diag) {  // mask: kv_local <= q_local
                int c = f * 16 + quad * 4;
                p0 = (c + 0 <= qr16) ? p0 : 0.f;
                p1 = (c + 1 <= qr16) ? p1 : 0.f;
                p2 = (c + 2 <= qr16) ? p2 : 0.f;
                p3 = (c + 3 <= qr16) ? p3 : 0.f;
            }
            lacc += (p0 + p1) + (p2 + p3);
            unsigned int d0, d1;
            asm("v_cvt_pk_bf16_f32 %0, %1, %2" : "=v"(d0) : "v"(p0), "v"(p1));
            asm("v_cvt_pk_bf16_f32 %0, %1, %2" : "=v"(d1) : "v"(p2), "v"(p3));
            *(uint2*)&sP[w][l16 * 72 + f * 16 + quad * 4] = (uint2){d0, d1};
        }
        asm volatile("" ::: "memory");  // order P stores before reload
        bf16x8 pf0 = *(const bf16x8*)&sP[w][l16 * 72 + quad * 8];
        bf16x8 pf1 = *(const bf16x8*)&sP[w][l16 * 72 + 32 + quad * 8];
#pragma unroll
        for (int nt = 0; nt < 4; ++nt) {
            bf16x8 v0 = *(const bf16x8*)&sV[(nt * 16 + l16) * 72 + quad * 8];
            bf16x8 v1 = *(const bf16x8*)&sV[(nt * 16 + l16) * 72 + 32 + quad * 8];
            o[nt] = __builtin_amdgcn_mfma_f32_16x16x32_bf16(pf0, v0, o[nt], 0, 0, 0);
            o[nt] = __builtin_amdgcn_mfma_f32_16x16x32_bf16(pf1, v1, o[nt], 0, 0, 0);
        }
    }

    // lacc holds a partial denom for q=q0+l16 (this thread's kv subset).
    // Full denom: sum over the 4 quads (lanes sharing l16).
    lacc += __shfl_xor(lacc, 16);
    lacc += __shfl_xor(lacc, 32);
    // Output rows of this thread are q0 + quad*4 + r; their denoms live in
    // lanes (quad*4+r) (which have l16 == quad*4+r).
    float lt[4];
#pragma unroll
    for (int r = 0; r < 4; ++r) lt[r] = __shfl(lacc, quad * 4 + r);

    unsigned short* yb = y + (size_t)(b * 2048) * 1024 + h * 64;
#pragma unroll
    for (int nt = 0; nt < 4; ++nt)
#pragma unroll
        for (int r = 0; r < 4; ++r)
            yb[(size_t)(q0 + quad * 4 + r) * 1024 + nt * 16 + l16] =
                f2bf(o[nt][r] / lt[r]);
}

// -------------------------------------------------------------------------
extern "C" void kernel_launch(void* const* d_in, const int* in_sizes, int n_in,
                              void* d_out, int out_size, void* d_ws, size_t ws_size,
                              hipStream_t stream) {
    const float* x       = (const float*)d_in[0];
    const float* w_attn  = (const float*)d_in[1];
    const float* b_attn  = (const float*)d_in[2];
    const float* la_attn = (const float*)d_in[3];
    const float* lb_attn = (const float*)d_in[4];
    const float* w_proj  = (const float*)d_in[5];
    const float* b_proj  = (const float*)d_in[6];
    const float* la_proj = (const float*)d_in[7];
    const float* lb_proj = (const float*)d_in[8];
    float* out = (float*)d_out;

    char* w = (char*)d_ws;
    unsigned short* xb        = (unsigned short*)w; w += (size_t)4096 * 1024 * 2;
    unsigned short* Weff_attn = (unsigned short*)w; w += (size_t)3072 * 1024 * 2;
    unsigned short* Weff_proj = (unsigned short*)w; w += (size_t)1024 * 1024 * 2;
    unsigned short* qkv       = (unsigned short*)w; w += (size_t)4096 * 3072 * 2;
    unsigned short* Vt        = (unsigned short*)w; w += (size_t)32 * 64 * 2048 * 2;
    unsigned short* y         = (unsigned short*)w; w += (size_t)4096 * 1024 * 2;

    prep<<<4096, 256, 0, stream>>>(x, xb, w_attn, la_attn, lb_attn, Weff_attn,
                                   w_proj, la_proj, lb_proj, Weff_proj);
    gemm_bt_bias<false, true><<<dim3(24, 32), 256, 0, stream>>>(
        xb, Weff_attn, b_attn, qkv, (float*)nullptr, Vt, 4096, 3072, 1024);
    attn_kernel<<<dim3(32, 16, 2), 256, 0, stream>>>(qkv, Vt, y);
    gemm_bt_bias64<<<dim3(8, 64), 256, 0, stream>>>(
        y, Weff_proj, b_proj, out, 4096, 1024, 1024);
}

// Round 11
// 188.075 us; speedup vs baseline: 1.1176x; 1.0586x over previous
//
#include <hip/hip_runtime.h>

typedef __attribute__((ext_vector_type(8))) short bf16x8;
typedef __attribute__((ext_vector_type(4))) short bf16x4;
typedef __attribute__((ext_vector_type(4))) float f32x4;

__device__ __forceinline__ float bf2f(unsigned short u) {
    unsigned int x = ((unsigned int)u) << 16;
    float f;
    __builtin_memcpy(&f, &x, 4);
    return f;
}
__device__ __forceinline__ unsigned short f2bf(float f) {
    unsigned int x;
    __builtin_memcpy(&x, &f, 4);
    x += 0x7FFFu + ((x >> 16) & 1u);
    return (unsigned short)(x >> 16);
}

// Async global->LDS: HW writes lds[base + lane*16]; gptr is per-lane.
#define GLOAD_LDS16(gp, lp)                                      \
    __builtin_amdgcn_global_load_lds(                            \
        (const __attribute__((address_space(1))) void*)(gp),     \
        (__attribute__((address_space(3))) void*)(lp), 16, 0, 0)

// -------------------------------------------------------------------------
// Fused preprocessing, G13-vectorized: 8 elems/thread, float4 x2 loads,
// one 16B bf16x8 store.
// blocks [0,2048):       cast x f32 -> bf16      (4096x1024)
// blocks [2048,3584):    fold_lora attn          (3072x1024)
// blocks [3584,4096):    fold_lora proj          (1024x1024)
__global__ __launch_bounds__(256) void prep(
    const float* __restrict__ x, unsigned short* __restrict__ xb,
    const float* __restrict__ w_attn, const float* __restrict__ la_attn,
    const float* __restrict__ lb_attn, unsigned short* __restrict__ Weff_attn,
    const float* __restrict__ w_proj, const float* __restrict__ la_proj,
    const float* __restrict__ lb_proj, unsigned short* __restrict__ Weff_proj) {
    const int bid = blockIdx.x;
    if (bid < 2048) {
        int i = (bid * 256 + threadIdx.x) * 8;
        float4 v0 = *(const float4*)(x + i);
        float4 v1 = *(const float4*)(x + i + 4);
        bf16x8 o;
        o[0] = (short)f2bf(v0.x); o[1] = (short)f2bf(v0.y);
        o[2] = (short)f2bf(v0.z); o[3] = (short)f2bf(v0.w);
        o[4] = (short)f2bf(v1.x); o[5] = (short)f2bf(v1.y);
        o[6] = (short)f2bf(v1.z); o[7] = (short)f2bf(v1.w);
        *(bf16x8*)(xb + i) = o;
        return;
    }
    const float* W;
    const float* Ain;
    const float* Bin;
    unsigned short* Weff;
    int idx;
    if (bid < 3584) {
        idx = ((bid - 2048) * 256 + threadIdx.x) * 8;
        W = w_attn; Ain = la_attn; Bin = lb_attn; Weff = Weff_attn;
    } else {
        idx = ((bid - 3584) * 256 + threadIdx.x) * 8;
        W = w_proj; Ain = la_proj; Bin = lb_proj; Weff = Weff_proj;
    }
    const int n = idx >> 10;
    const int k = idx & 1023;
    float s[8];
#pragma unroll
    for (int j = 0; j < 8; ++j) s[j] = 0.f;
#pragma unroll
    for (int r = 0; r < 16; ++r) {
        const float bcoef = Bin[n * 16 + r];
        float4 a0 = *(const float4*)(Ain + r * 1024 + k);
        float4 a1 = *(const float4*)(Ain + r * 1024 + k + 4);
        s[0] += bcoef * a0.x; s[1] += bcoef * a0.y;
        s[2] += bcoef * a0.z; s[3] += bcoef * a0.w;
        s[4] += bcoef * a1.x; s[5] += bcoef * a1.y;
        s[6] += bcoef * a1.z; s[7] += bcoef * a1.w;
    }
    float4 w0 = *(const float4*)(W + idx);
    float4 w1 = *(const float4*)(W + idx + 4);
    bf16x8 o;
    o[0] = (short)f2bf(w0.x + 0.0625f * s[0]);
    o[1] = (short)f2bf(w0.y + 0.0625f * s[1]);
    o[2] = (short)f2bf(w0.z + 0.0625f * s[2]);
    o[3] = (short)f2bf(w0.w + 0.0625f * s[3]);
    o[4] = (short)f2bf(w1.x + 0.0625f * s[4]);
    o[5] = (short)f2bf(w1.y + 0.0625f * s[5]);
    o[6] = (short)f2bf(w1.z + 0.0625f * s[6]);
    o[7] = (short)f2bf(w1.w + 0.0625f * s[7]);
    *(bf16x8*)(Weff + idx) = o;
}

// -------------------------------------------------------------------------
// C[M][N] = A[M][K] @ B[N][K]^T + bias[N].  A,B bf16; bias float; fp32 acc.
// T3-minimum 2-phase double-buffer: issue next K-tile's global_load_lds into
// buf^1 FIRST, compute on buf, then ONE barrier (its vmcnt(0) lands after the
// MFMA phase has covered the load latency). Was: drain-before-compute, 2
// barriers/K-step -- the §5 barrier-drain stall, costly at K=1024 (32 steps).
// Manually 2x-unrolled so buffer selection is compile-time.
// VSPLIT (qkv GEMM): tiles with n0 >= 2048 are the V third of qkv; written
// transposed directly into Vt (replaces the transpose_v kernel).
template <bool F32OUT, bool VSPLIT>
__global__ __launch_bounds__(256) void gemm_bt_bias(
    const unsigned short* __restrict__ A, const unsigned short* __restrict__ B,
    const float* __restrict__ bias, unsigned short* __restrict__ Cb,
    float* __restrict__ Cf, unsigned short* __restrict__ Vtout,
    int M, int N, int K) {
    __shared__ unsigned short sA0[128 * 32], sA1[128 * 32];
    __shared__ unsigned short sB0[128 * 32], sB1[128 * 32];
    const int tid = threadIdx.x;
    const int wave = tid >> 6, lane = tid & 63;
    const int quad = lane >> 4, l16 = lane & 15;
    const int m0 = blockIdx.y * 128, n0 = blockIdx.x * 128;
    const int wm = (wave & 1) * 64, wn = (wave >> 1) * 64;

    const int srow = wave * 32 + (lane >> 2);
    const int scol = (lane & 3) * 8;
    const unsigned short* Ag = A + (size_t)(m0 + srow) * K + scol;
    const unsigned short* Bg = B + (size_t)(n0 + srow) * K + scol;
    const int woff = wave * 1024;
    const size_t kjump = (size_t)16 * K;

    f32x4 acc[4][4];
#pragma unroll
    for (int i = 0; i < 4; ++i)
#pragma unroll
        for (int j = 0; j < 4; ++j) acc[i][j] = (f32x4){0.f, 0.f, 0.f, 0.f};

    auto stage = [&](unsigned short* dA, unsigned short* dB, int k) {
        GLOAD_LDS16(Ag + k, dA + woff);
        GLOAD_LDS16(Ag + k + kjump, dA + woff + 512);
        GLOAD_LDS16(Bg + k, dB + woff);
        GLOAD_LDS16(Bg + k + kjump, dB + woff + 512);
    };
    auto compute = [&](const unsigned short* cA, const unsigned short* cB) {
        bf16x8 af[4], bfr[4];
#pragma unroll
        for (int mi = 0; mi < 4; ++mi)
            af[mi] = *(const bf16x8*)&cA[(wm + mi * 16 + l16) * 32 + quad * 8];
#pragma unroll
        for (int ni = 0; ni < 4; ++ni)
            bfr[ni] = *(const bf16x8*)&cB[(wn + ni * 16 + l16) * 32 + quad * 8];
#pragma unroll
        for (int mi = 0; mi < 4; ++mi)
#pragma unroll
            for (int ni = 0; ni < 4; ++ni)
                acc[mi][ni] = __builtin_amdgcn_mfma_f32_16x16x32_bf16(
                    af[mi], bfr[ni], acc[mi][ni], 0, 0, 0);
    };

    stage(sA0, sB0, 0);
    __syncthreads();  // tile 0 resident (vmcnt(0) drained by barrier)
    for (int k0 = 0; k0 < K; k0 += 64) {
        if (k0 + 32 < K) stage(sA1, sB1, k0 + 32);  // in flight during MFMA
        compute(sA0, sB0);
        __syncthreads();  // next tile resident; buf0 reads done
        if (k0 + 64 < K) stage(sA0, sB0, k0 + 64);
        compute(sA1, sB1);
        __syncthreads();
    }

    float bv[4];
#pragma unroll
    for (int ni = 0; ni < 4; ++ni) bv[ni] = bias[n0 + wn + ni * 16 + l16];

    if (VSPLIT && n0 >= 2048) {
#pragma unroll
        for (int ni = 0; ni < 4; ++ni) {
            const int hcol = n0 + wn + ni * 16 + l16 - 2048;
#pragma unroll
            for (int mi = 0; mi < 4; ++mi) {
                const int rowtop = m0 + wm + mi * 16 + quad * 4;
                const int bb = rowtop >> 11;
                const int t = rowtop & 2047;
                bf16x4 pk;
#pragma unroll
                for (int r = 0; r < 4; ++r)
                    pk[r] = (short)f2bf(acc[mi][ni][r] + bv[ni]);
                *(bf16x4*)(Vtout +
                           ((size_t)((bb * 16 + (hcol >> 6)) * 64 + (hcol & 63))) *
                               2048 +
                           t) = pk;
            }
        }
        return;
    }

#pragma unroll
    for (int mi = 0; mi < 4; ++mi)
#pragma unroll
        for (int ni = 0; ni < 4; ++ni)
#pragma unroll
            for (int r = 0; r < 4; ++r) {
                int row = m0 + wm + mi * 16 + quad * 4 + r;
                int col = n0 + wn + ni * 16 + l16;
                float val = acc[mi][ni][r] + bv[ni];
                if (F32OUT)
                    Cf[(size_t)row * N + col] = val;
                else
                    Cb[(size_t)row * N + col] = f2bf(val);
            }
}

// -------------------------------------------------------------------------
// BM=64 variant for the proj GEMM, same 2-phase double-buffer.
// Grid (N/128, M/64) = (8,64) = 512 blocks = 2 blocks/CU.
__global__ __launch_bounds__(256) void gemm_bt_bias64(
    const unsigned short* __restrict__ A, const unsigned short* __restrict__ B,
    const float* __restrict__ bias, float* __restrict__ Cf,
    int M, int N, int K) {
    __shared__ unsigned short sA0[64 * 32], sA1[64 * 32];
    __shared__ unsigned short sB0[128 * 32], sB1[128 * 32];
    const int tid = threadIdx.x;
    const int wave = tid >> 6, lane = tid & 63;
    const int quad = lane >> 4, l16 = lane & 15;
    const int m0 = blockIdx.y * 64, n0 = blockIdx.x * 128;
    const int wn = wave * 32;

    const int srowA = wave * 16 + (lane >> 2);
    const int srowB = wave * 32 + (lane >> 2);
    const int scol = (lane & 3) * 8;
    const unsigned short* Ag = A + (size_t)(m0 + srowA) * K + scol;
    const unsigned short* Bg = B + (size_t)(n0 + srowB) * K + scol;
    const int woffA = wave * 512, woffB = wave * 1024;
    const size_t kjump = (size_t)16 * K;

    f32x4 acc[4][2];
#pragma unroll
    for (int i = 0; i < 4; ++i)
#pragma unroll
        for (int j = 0; j < 2; ++j) acc[i][j] = (f32x4){0.f, 0.f, 0.f, 0.f};

    auto stage = [&](unsigned short* dA, unsigned short* dB, int k) {
        GLOAD_LDS16(Ag + k, dA + woffA);
        GLOAD_LDS16(Bg + k, dB + woffB);
        GLOAD_LDS16(Bg + k + kjump, dB + woffB + 512);
    };
    auto compute = [&](const unsigned short* cA, const unsigned short* cB) {
        bf16x8 af[4], bfr[2];
#pragma unroll
        for (int mi = 0; mi < 4; ++mi)
            af[mi] = *(const bf16x8*)&cA[(mi * 16 + l16) * 32 + quad * 8];
#pragma unroll
        for (int ni = 0; ni < 2; ++ni)
            bfr[ni] = *(const bf16x8*)&cB[(wn + ni * 16 + l16) * 32 + quad * 8];
#pragma unroll
        for (int mi = 0; mi < 4; ++mi)
#pragma unroll
            for (int ni = 0; ni < 2; ++ni)
                acc[mi][ni] = __builtin_amdgcn_mfma_f32_16x16x32_bf16(
                    af[mi], bfr[ni], acc[mi][ni], 0, 0, 0);
    };

    stage(sA0, sB0, 0);
    __syncthreads();
    for (int k0 = 0; k0 < K; k0 += 64) {
        if (k0 + 32 < K) stage(sA1, sB1, k0 + 32);
        compute(sA0, sB0);
        __syncthreads();
        if (k0 + 64 < K) stage(sA0, sB0, k0 + 64);
        compute(sA1, sB1);
        __syncthreads();
    }

    float bv[2];
#pragma unroll
    for (int ni = 0; ni < 2; ++ni) bv[ni] = bias[n0 + wn + ni * 16 + l16];
#pragma unroll
    for (int mi = 0; mi < 4; ++mi)
#pragma unroll
        for (int ni = 0; ni < 2; ++ni)
#pragma unroll
            for (int r = 0; r < 4; ++r) {
                int row = m0 + mi * 16 + quad * 4 + r;
                int col = n0 + wn + ni * 16 + l16;
                Cf[(size_t)row * N + col] = acc[mi][ni][r] + bv[ni];
            }
}

// -------------------------------------------------------------------------
// Flash attention v9: r3 scheduling (grid 32, balanced qblk permutation,
// 4 blocks/CU) + swapped-QK^T in-register softmax + prefetch issued after
// the second barrier. (v10's 2-q-frag variant regressed: occupancy halved.)
__global__ __launch_bounds__(256) void attn_kernel(
    const unsigned short* __restrict__ qkv,  // [4096][3072] bf16
    const unsigned short* __restrict__ Vt,   // [32][64][2048] bf16
    unsigned short* __restrict__ y) {        // [4096][1024] bf16
    const int b = blockIdx.z, h = blockIdx.y;
    const int bh = b * 16 + h;
    const int qblk = (int)blockIdx.x ^ (((bh >> 3) & 1) ? 31 : 0);
    const int w = threadIdx.x >> 6, lane = threadIdx.x & 63;
    const int quad = lane >> 4, l16 = lane & 15;
    const int q0 = qblk * 64 + w * 16;
    const int ntiles = qblk + 1;

    __shared__ unsigned short sK[64 * 72];     // [kv][d]
    __shared__ unsigned short sV[64 * 72];     // [d][kv]
    __shared__ unsigned short sP[4][16 * 72];  // per-wave P [q][kv]

    const unsigned short* Qb = qkv + (size_t)(b * 2048) * 3072 + h * 64;
    const unsigned short* Kg = Qb + 1024;
    const unsigned short* Vg = Vt + (size_t)(bh * 64) * 2048;

    const int rlo = threadIdx.x >> 3;       // 0..31
    const int c8 = (threadIdx.x & 7) * 8;   // 0..56

    bf16x8 qf0 = *(const bf16x8*)(Qb + (size_t)(q0 + l16) * 3072 + quad * 8);
    bf16x8 qf1 = *(const bf16x8*)(Qb + (size_t)(q0 + l16) * 3072 + 32 + quad * 8);

    f32x4 o[4];
    float lacc = 0.f;  // scalar: all this thread's P values belong to q=q0+l16
#pragma unroll
    for (int nt = 0; nt < 4; ++nt) o[nt] = (f32x4){0.f, 0.f, 0.f, 0.f};

    const float csc = 0.125f * 1.44269504088896340736f;  // (1/sqrt 64)*log2(e)

    bf16x8 kr0 = *(const bf16x8*)(Kg + (size_t)rlo * 3072 + c8);
    bf16x8 kr1 = *(const bf16x8*)(Kg + (size_t)(rlo + 32) * 3072 + c8);
    bf16x8 vr0 = *(const bf16x8*)(Vg + (size_t)rlo * 2048 + c8);
    bf16x8 vr1 = *(const bf16x8*)(Vg + (size_t)(rlo + 32) * 2048 + c8);

    for (int it = 0; it < ntiles; ++it) {
        const int kv0 = it * 64;
        __syncthreads();  // buffer free; drains last iter's prefetch (cheap)
        *(bf16x8*)&sK[rlo * 72 + c8] = kr0;
        *(bf16x8*)&sK[(rlo + 32) * 72 + c8] = kr1;
        *(bf16x8*)&sV[rlo * 72 + c8] = vr0;
        *(bf16x8*)&sV[(rlo + 32) * 72 + c8] = vr1;
        __syncthreads();  // buffer ready (no vmem outstanding here)
        if (it + 1 < ntiles) {  // prefetch next tile: in flight during compute
            const int nx = kv0 + 64;
            kr0 = *(const bf16x8*)(Kg + (size_t)(nx + rlo) * 3072 + c8);
            kr1 = *(const bf16x8*)(Kg + (size_t)(nx + rlo + 32) * 3072 + c8);
            vr0 = *(const bf16x8*)(Vg + (size_t)rlo * 2048 + nx + c8);
            vr1 = *(const bf16x8*)(Vg + (size_t)(rlo + 32) * 2048 + nx + c8);
        }

        // S^T[f][r]: q = q0+l16, kv = kv0 + f*16 + quad*4 + r
        f32x4 S[4];
#pragma unroll
        for (int f = 0; f < 4; ++f) {
            bf16x8 klo = *(const bf16x8*)&sK[(f * 16 + l16) * 72 + quad * 8];
            bf16x8 khi = *(const bf16x8*)&sK[(f * 16 + l16) * 72 + 32 + quad * 8];
            S[f] = (f32x4){0.f, 0.f, 0.f, 0.f};
            S[f] = __builtin_amdgcn_mfma_f32_16x16x32_bf16(klo, qf0, S[f], 0, 0, 0);
            S[f] = __builtin_amdgcn_mfma_f32_16x16x32_bf16(khi, qf1, S[f], 0, 0, 0);
        }
        const bool diag = (it == qblk);
        const int qr16 = w * 16 + l16;  // q position within the 64-row block
#pragma unroll
        for (int f = 0; f < 4; ++f) {
            float p0, p1, p2, p3;
            {
                float sv = S[f][0] * csc;
                asm("v_exp_f32 %0, %1" : "=v"(p0) : "v"(sv));
                sv = S[f][1] * csc;
                asm("v_exp_f32 %0, %1" : "=v"(p1) : "v"(sv));
                sv = S[f][2] * csc;
                asm("v_exp_f32 %0, %1" : "=v"(p2) : "v"(sv));
                sv = S[f][3] * csc;
                asm("v_exp_f32 %0, %1" : "=v"(p3) : "v"(sv));
            }
            if (diag) {  // mask: kv_local <= q_local
                int c = f * 16 + quad * 4;
                p0 = (c + 0 <= qr16) ? p0 : 0.f;
                p1 = (c + 1 <= qr16) ? p1 : 0.f;
                p2 = (c + 2 <= qr16) ? p2 : 0.f;
                p3 = (c + 3 <= qr16) ? p3 : 0.f;
            }
            lacc += (p0 + p1) + (p2 + p3);
            unsigned int d0, d1;
            asm("v_cvt_pk_bf16_f32 %0, %1, %2" : "=v"(d0) : "v"(p0), "v"(p1));
            asm("v_cvt_pk_bf16_f32 %0, %1, %2" : "=v"(d1) : "v"(p2), "v"(p3));
            *(uint2*)&sP[w][l16 * 72 + f * 16 + quad * 4] = (uint2){d0, d1};
        }
        asm volatile("" ::: "memory");  // order P stores before reload
        bf16x8 pf0 = *(const bf16x8*)&sP[w][l16 * 72 + quad * 8];
        bf16x8 pf1 = *(const bf16x8*)&sP[w][l16 * 72 + 32 + quad * 8];
#pragma unroll
        for (int nt = 0; nt < 4; ++nt) {
            bf16x8 v0 = *(const bf16x8*)&sV[(nt * 16 + l16) * 72 + quad * 8];
            bf16x8 v1 = *(const bf16x8*)&sV[(nt * 16 + l16) * 72 + 32 + quad * 8];
            o[nt] = __builtin_amdgcn_mfma_f32_16x16x32_bf16(pf0, v0, o[nt], 0, 0, 0);
            o[nt] = __builtin_amdgcn_mfma_f32_16x16x32_bf16(pf1, v1, o[nt], 0, 0, 0);
        }
    }

    // lacc holds a partial denom for q=q0+l16 (this thread's kv subset).
    // Full denom: sum over the 4 quads (lanes sharing l16).
    lacc += __shfl_xor(lacc, 16);
    lacc += __shfl_xor(lacc, 32);
    // Output rows of this thread are q0 + quad*4 + r; their denoms live in
    // lanes (quad*4+r) (which have l16 == quad*4+r).
    float lt[4];
#pragma unroll
    for (int r = 0; r < 4; ++r) lt[r] = __shfl(lacc, quad * 4 + r);

    unsigned short* yb = y + (size_t)(b * 2048) * 1024 + h * 64;
#pragma unroll
    for (int nt = 0; nt < 4; ++nt)
#pragma unroll
        for (int r = 0; r < 4; ++r)
            yb[(size_t)(q0 + quad * 4 + r) * 1024 + nt * 16 + l16] =
                f2bf(o[nt][r] / lt[r]);
}

// -------------------------------------------------------------------------
extern "C" void kernel_launch(void* const* d_in, const int* in_sizes, int n_in,
                              void* d_out, int out_size, void* d_ws, size_t ws_size,
                              hipStream_t stream) {
    const float* x       = (const float*)d_in[0];
    const float* w_attn  = (const float*)d_in[1];
    const float* b_attn  = (const float*)d_in[2];
    const float* la_attn = (const float*)d_in[3];
    const float* lb_attn = (const float*)d_in[4];
    const float* w_proj  = (const float*)d_in[5];
    const float* b_proj  = (const float*)d_in[6];
    const float* la_proj = (const float*)d_in[7];
    const float* lb_proj = (const float*)d_in[8];
    float* out = (float*)d_out;

    char* w = (char*)d_ws;
    unsigned short* xb        = (unsigned short*)w; w += (size_t)4096 * 1024 * 2;
    unsigned short* Weff_attn = (unsigned short*)w; w += (size_t)3072 * 1024 * 2;
    unsigned short* Weff_proj = (unsigned short*)w; w += (size_t)1024 * 1024 * 2;
    unsigned short* qkv       = (unsigned short*)w; w += (size_t)4096 * 3072 * 2;
    unsigned short* Vt        = (unsigned short*)w; w += (size_t)32 * 64 * 2048 * 2;
    unsigned short* y         = (unsigned short*)w; w += (size_t)4096 * 1024 * 2;

    prep<<<4096, 256, 0, stream>>>(x, xb, w_attn, la_attn, lb_attn, Weff_attn,
                                   w_proj, la_proj, lb_proj, Weff_proj);
    gemm_bt_bias<false, true><<<dim3(24, 32), 256, 0, stream>>>(
        xb, Weff_attn, b_attn, qkv, (float*)nullptr, Vt, 4096, 3072, 1024);
    attn_kernel<<<dim3(32, 16, 2), 256, 0, stream>>>(qkv, Vt, y);
    gemm_bt_bias64<<<dim3(8, 64), 256, 0, stream>>>(
        y, Weff_proj, b_proj, out, 4096, 1024, 1024);
}